// Round 1
// baseline (276.573 us; speedup 1.0000x reference)
//
#include <hip/hip_runtime.h>
#include <math.h>

// Problem constants
// N_AGENTS=16, RNN_H=64, N_HEADS=4, GAT_D=32, EMB=32, SDIM=128, B=4096 rows

// ---------------------------------------------------------------------------
// K1: per-row GAT (hp, attention, g) + small GEMVs (b1, wf, v)
// one block per row, 256 threads
// ---------------------------------------------------------------------------
__global__ __launch_bounds__(256) void k1_gat(
    const float* __restrict__ states,
    const float* __restrict__ hidden_states,
    const float* __restrict__ W_gat,     // [64][128]
    const float* __restrict__ att_a,     // [4][64]
    const float* __restrict__ b1_W, const float* __restrict__ b1_b,
    const float* __restrict__ wf_W, const float* __restrict__ wf_b,
    const float* __restrict__ V1_W, const float* __restrict__ V1_b,
    const float* __restrict__ V2_W, const float* __restrict__ V2_b,
    float* __restrict__ g_out,           // [B][4][16][32]
    float* __restrict__ b1_out,          // [B][32]
    float* __restrict__ wf_out,          // [B][32]
    float* __restrict__ v_out)           // [B]
{
    const int b = blockIdx.x, tid = threadIdx.x;
    __shared__ float hs[1024];       // [16][64]
    __shared__ float sv[128];
    __shared__ float hp[16 * 132];   // [n][c], padded stride
    __shared__ float attn[1024];     // [h][i][j]
    __shared__ float srcv[64], dstv[64], red[32];

    for (int i = tid; i < 1024; i += 256) hs[i] = hidden_states[b * 1024 + i];
    if (tid < 128) sv[tid] = states[b * 128 + tid];
    __syncthreads();

    // hp[n][c] = sum_k hs[n][k] * W_gat[k][c]
    #pragma unroll
    for (int e = 0; e < 8; ++e) {
        int idx = e * 256 + tid;
        int n = idx >> 7, c = idx & 127;
        float acc = 0.f;
        #pragma unroll 8
        for (int k = 0; k < 64; ++k) acc = fmaf(hs[n * 64 + k], W_gat[k * 128 + c], acc);
        hp[n * 132 + c] = acc;
    }
    __syncthreads();

    // src/dst projections
    if (tid < 64) {
        int h = tid >> 4, n = tid & 15;
        float as = 0.f, ad = 0.f;
        #pragma unroll
        for (int d = 0; d < 32; ++d) {
            float x = hp[n * 132 + h * 32 + d];
            as = fmaf(x, att_a[h * 64 + d], as);
            ad = fmaf(x, att_a[h * 64 + 32 + d], ad);
        }
        srcv[tid] = as; dstv[tid] = ad;
    }
    __syncthreads();

    // attention: leaky_relu(src_i + dst_j, 0.2) -> softmax over j
    if (tid < 64) {
        int h = tid >> 4;
        float si = srcv[tid];
        float ev[16];
        float m = -1e30f;
        #pragma unroll
        for (int j = 0; j < 16; ++j) {
            float x = si + dstv[h * 16 + j];
            x = (x >= 0.f) ? x : 0.2f * x;
            ev[j] = x; m = fmaxf(m, x);
        }
        float ssum = 0.f;
        #pragma unroll
        for (int j = 0; j < 16; ++j) { float p = expf(ev[j] - m); ev[j] = p; ssum += p; }
        float inv = 1.f / ssum;
        #pragma unroll
        for (int j = 0; j < 16; ++j) attn[tid * 16 + j] = ev[j] * inv;
    }
    __syncthreads();

    // g[h][i][d] = elu(sum_j attn[h][i][j] * hp[j][h*32+d])
    #pragma unroll
    for (int e = 0; e < 8; ++e) {
        int idx = e * 256 + tid;
        int h = idx >> 9, i = (idx >> 5) & 15, d = idx & 31;
        float acc = 0.f;
        #pragma unroll
        for (int j = 0; j < 16; ++j)
            acc = fmaf(attn[(h * 16 + i) * 16 + j], hp[j * 132 + h * 32 + d], acc);
        acc = (acc > 0.f) ? acc : expm1f(acc);
        g_out[(size_t)b * 2048 + idx] = acc;
    }

    // small GEMVs: b1, wf (abs), V1->relu->V2 (v)
    if (tid < 96) {
        int which = tid >> 5, e = tid & 31;
        const float* Wm = (which == 0) ? b1_W : ((which == 1) ? wf_W : V1_W);
        float acc = 0.f;
        #pragma unroll 8
        for (int k = 0; k < 128; ++k) acc = fmaf(sv[k], Wm[k * 32 + e], acc);
        if (which == 0)      b1_out[b * 32 + e] = acc + b1_b[e];
        else if (which == 1) wf_out[b * 32 + e] = fabsf(acc + wf_b[e]);
        else                 red[e] = fmaxf(acc + V1_b[e], 0.f) * V2_W[e];
    }
    __syncthreads();
    if (tid == 0) {
        float acc = V2_b[0];
        #pragma unroll
        for (int e = 0; e < 32; ++e) acc += red[e];
        v_out[b] = acc;
    }
}

// ---------------------------------------------------------------------------
// K2a: w1_state = s_aug @ w1s_W + w1s_b   (M=4096, N=4096, K=129)
// classic tiled GEMM: 128x128 tile, 8x8 microtile, Kc=16 (zero-padded chunks)
// ---------------------------------------------------------------------------
__global__ __launch_bounds__(256) void k2a_gemm(
    const float* __restrict__ states,
    const float* __restrict__ uncertainty,
    const float* __restrict__ w1s_W,     // [129][4096]
    const float* __restrict__ w1s_b,     // [4096]
    float* __restrict__ w1state)         // [4096][4096]
{
    const int tid = threadIdx.x;
    const int row0 = blockIdx.x * 128, col0 = blockIdx.y * 128;
    __shared__ float As[16 * 132];   // [kk][r]
    __shared__ float Bs[16 * 132];   // [kk][c]
    const int tx = tid & 15, ty = tid >> 4;
    float acc[8][8] = {};

    for (int k0 = 0; k0 < 129; k0 += 16) {
        // stage A (transposed into [kk][r]); virtual col 128 = uncertainty
        for (int i = tid; i < 2048; i += 256) {
            int r = i >> 4, kk = i & 15;
            int k = k0 + kk;
            float v = 0.f;
            if (k < 128)       v = states[(size_t)(row0 + r) * 128 + k];
            else if (k == 128) v = uncertainty[row0 + r];
            As[kk * 132 + r] = v;
        }
        // stage B
        for (int i = tid; i < 2048; i += 256) {
            int kk = i >> 7, c = i & 127;
            int k = k0 + kk;
            Bs[kk * 132 + c] = (k <= 128) ? w1s_W[(size_t)k * 4096 + col0 + c] : 0.f;
        }
        __syncthreads();
        #pragma unroll 4
        for (int kk = 0; kk < 16; ++kk) {
            float a8[8], b8[8];
            *(float4*)&a8[0] = *(const float4*)&As[kk * 132 + ty * 8];
            *(float4*)&a8[4] = *(const float4*)&As[kk * 132 + ty * 8 + 4];
            *(float4*)&b8[0] = *(const float4*)&Bs[kk * 132 + tx * 8];
            *(float4*)&b8[4] = *(const float4*)&Bs[kk * 132 + tx * 8 + 4];
            #pragma unroll
            for (int i = 0; i < 8; ++i)
                #pragma unroll
                for (int j = 0; j < 8; ++j)
                    acc[i][j] = fmaf(a8[i], b8[j], acc[i][j]);
        }
        __syncthreads();
    }
    // epilogue: + bias, coalesced float4 stores
    #pragma unroll
    for (int i = 0; i < 8; ++i) {
        size_t row = row0 + ty * 8 + i;
        #pragma unroll
        for (int j = 0; j < 8; j += 4) {
            int col = col0 + tx * 8 + j;
            float4 bb = *(const float4*)&w1s_b[col];
            float4 o;
            o.x = acc[i][j + 0] + bb.x;
            o.y = acc[i][j + 1] + bb.y;
            o.z = acc[i][j + 2] + bb.z;
            o.w = acc[i][j + 3] + bb.w;
            *(float4*)&w1state[row * 4096 + col] = o;
        }
    }
}

// ---------------------------------------------------------------------------
// K2b: per-row: w1_heads = |w1_state . g| over d; fold qs, mean over h,
// b1, elu, w_final, v  ->  y[b]
// one block per row, 256 threads
// ---------------------------------------------------------------------------
__global__ __launch_bounds__(256) void k2b_final(
    const float* __restrict__ agent_qs,  // [B][16]
    const float* __restrict__ w1state,   // [B][4096]
    const float* __restrict__ g,         // [B][2048]
    const float* __restrict__ b1v,       // [B][32]
    const float* __restrict__ wfv,       // [B][32]
    const float* __restrict__ vv,        // [B]
    float* __restrict__ out)             // [B]
{
    const int b = blockIdx.x, tid = threadIdx.x;
    __shared__ float ws1[4 * 32 * 36];   // [h][e][d] stride 36 (16B aligned)
    __shared__ float gs[4 * 16 * 36];    // [h][n][d] stride 36
    __shared__ float qs[16];
    __shared__ float w1c[2048];          // [h][e][n]
    __shared__ float red[32];

    for (int i = tid; i < 4096; i += 256) {
        int he = i >> 5, d = i & 31;
        ws1[he * 36 + d] = w1state[(size_t)b * 4096 + i];
    }
    for (int i = tid; i < 2048; i += 256) {
        int hn = i >> 5, d = i & 31;
        gs[hn * 36 + d] = g[(size_t)b * 2048 + i];
    }
    if (tid < 16) qs[tid] = agent_qs[b * 16 + tid];
    __syncthreads();

    // w1c[h][e][n] = |sum_d w1_state[h][e][d]*g[h][n][d]| * qs[n]
    #pragma unroll
    for (int p = tid; p < 2048; p += 256) {
        int h = p >> 9, e = (p >> 4) & 31, n = p & 15;
        const float* wrow = &ws1[(h * 32 + e) * 36];
        const float* grow = &gs[(h * 16 + n) * 36];
        float acc = 0.f;
        #pragma unroll
        for (int d = 0; d < 32; ++d) acc = fmaf(wrow[d], grow[d], acc);
        w1c[(h * 32 + e) * 16 + n] = fabsf(acc) * qs[n];
    }
    __syncthreads();

    if (tid < 32) {
        int e = tid;
        float s = 0.f;
        #pragma unroll
        for (int h = 0; h < 4; ++h)
            #pragma unroll
            for (int n = 0; n < 16; ++n) s += w1c[(h * 32 + e) * 16 + n];
        float hid = 0.25f * s + b1v[b * 32 + e];
        hid = (hid > 0.f) ? hid : expm1f(hid);
        red[e] = hid * wfv[b * 32 + e];
    }
    __syncthreads();
    if (tid == 0) {
        float y = vv[b];
        #pragma unroll
        for (int e = 0; e < 32; ++e) y += red[e];
        out[b] = y;
    }
}

// ---------------------------------------------------------------------------
extern "C" void kernel_launch(void* const* d_in, const int* in_sizes, int n_in,
                              void* d_out, int out_size, void* d_ws, size_t ws_size,
                              hipStream_t stream)
{
    const float* agent_qs      = (const float*)d_in[0];
    const float* states        = (const float*)d_in[1];
    const float* hidden_states = (const float*)d_in[2];
    const float* uncertainty   = (const float*)d_in[3];
    const float* W_gat         = (const float*)d_in[4];
    const float* att_a         = (const float*)d_in[5];
    const float* w1s_W         = (const float*)d_in[6];
    const float* w1s_b         = (const float*)d_in[7];
    const float* b1_W          = (const float*)d_in[8];
    const float* b1_b          = (const float*)d_in[9];
    const float* wf_W          = (const float*)d_in[10];
    const float* wf_b          = (const float*)d_in[11];
    const float* V1_W          = (const float*)d_in[12];
    const float* V1_b          = (const float*)d_in[13];
    const float* V2_W          = (const float*)d_in[14];
    const float* V2_b          = (const float*)d_in[15];

    float* ws      = (float*)d_ws;
    float* g       = ws;                                   // 4096*2048
    float* w1state = g + (size_t)4096 * 2048;              // 4096*4096
    float* b1v     = w1state + (size_t)4096 * 4096;        // 4096*32
    float* wfv     = b1v + 4096 * 32;                      // 4096*32
    float* vv      = wfv + 4096 * 32;                      // 4096
    float* out     = (float*)d_out;

    k1_gat<<<4096, 256, 0, stream>>>(states, hidden_states, W_gat, att_a,
        b1_W, b1_b, wf_W, wf_b, V1_W, V1_b, V2_W, V2_b, g, b1v, wfv, vv);

    dim3 grid2(32, 32);
    k2a_gemm<<<grid2, 256, 0, stream>>>(states, uncertainty, w1s_W, w1s_b, w1state);

    k2b_final<<<4096, 256, 0, stream>>>(agent_qs, w1state, g, b1v, wfv, vv, out);
}

// Round 2
// 201.016 us; speedup vs baseline: 1.3759x; 1.3759x over previous
//
#include <hip/hip_runtime.h>
#include <math.h>
#include <string.h>

// N_AGENTS=16, RNN_H=64, N_HEADS=4, GAT_D=32, EMB=32, SDIM=128, B=4096 rows

typedef __attribute__((ext_vector_type(8))) short short8;
typedef __attribute__((ext_vector_type(8))) unsigned short ushort8;
typedef __attribute__((ext_vector_type(4))) float float4v;

static __device__ inline unsigned short f2bf(float f) {
    unsigned int x;
    __builtin_memcpy(&x, &f, 4);
    unsigned int r = x + 0x7fffu + ((x >> 16) & 1u);   // RNE
    return (unsigned short)(r >> 16);
}
static __device__ inline float bf2f(unsigned short u) {
    unsigned int x = ((unsigned int)u) << 16;
    float f;
    __builtin_memcpy(&f, &x, 4);
    return f;
}

// ---------------------------------------------------------------------------
// K0: bf16 conversions: states -> A_bf [4096][128]; w1s_W[0:128] -> w1sT_bf
// [4096 cols][128 k] (transposed, k-contiguous for MFMA B-frags)
// ---------------------------------------------------------------------------
__global__ __launch_bounds__(256) void k0_convert(
    const float* __restrict__ states,
    const float* __restrict__ w1s_W,
    unsigned short* __restrict__ A_bf,
    unsigned short* __restrict__ w1sT_bf)
{
    int idx = blockIdx.x * 256 + threadIdx.x;      // < 524288
    A_bf[idx] = f2bf(states[idx]);
    int k = idx >> 12, c = idx & 4095;             // coalesced read, scattered write
    w1sT_bf[c * 128 + k] = f2bf(w1s_W[idx]);
}

// ---------------------------------------------------------------------------
// K1: per-row GAT + small GEMVs. W_gat staged in LDS; vectorized hp / g loops.
// g written as bf16 for the fused MFMA consumer.
// ---------------------------------------------------------------------------
__global__ __launch_bounds__(256) void k1_gat(
    const float* __restrict__ states,
    const float* __restrict__ hidden_states,
    const float* __restrict__ W_gat,     // [64][128]
    const float* __restrict__ att_a,     // [4][64]
    const float* __restrict__ b1_W, const float* __restrict__ b1_b,
    const float* __restrict__ wf_W, const float* __restrict__ wf_b,
    const float* __restrict__ V1_W, const float* __restrict__ V1_b,
    const float* __restrict__ V2_W, const float* __restrict__ V2_b,
    unsigned short* __restrict__ g_bf,   // [B][4][16][32] bf16
    float* __restrict__ b1_out,          // [B][32]
    float* __restrict__ wf_out,          // [B][32]
    float* __restrict__ v_out)           // [B]
{
    const int b = blockIdx.x, tid = threadIdx.x;
    __shared__ float Wl[64 * 132];       // W_gat [k][c], padded
    __shared__ float hsl[16 * 68];       // hs [n][k], padded
    __shared__ float hp[16 * 132];       // hp [n][c], padded
    __shared__ float attn[4 * 16 * 17];  // [h][i][j], padded
    __shared__ float sv[128];
    __shared__ float srcv[64], dstv[64], red[32];

    // stage W_gat (float4 coalesced)
    #pragma unroll
    for (int t = 0; t < 8; ++t) {
        int i = t * 256 + tid;
        int k = i >> 5, c4 = i & 31;
        *(float4*)&Wl[k * 132 + c4 * 4] = *(const float4*)&W_gat[k * 128 + c4 * 4];
    }
    #pragma unroll
    for (int t = 0; t < 4; ++t) {
        int i = t * 256 + tid;
        int n = i >> 6, kk = i & 63;
        hsl[n * 68 + kk] = hidden_states[(size_t)b * 1024 + i];
    }
    if (tid < 128) sv[tid] = states[b * 128 + tid];
    __syncthreads();

    // hp[n][c]: thread owns (n = tid>>4, 8 consecutive c at c8 = tid&15)
    {
        const int n = tid >> 4, c8 = tid & 15;
        float acc[8] = {};
        const float* hrow = &hsl[n * 68];
        #pragma unroll 8
        for (int k = 0; k < 64; ++k) {
            float hv = hrow[k];
            float4 w0 = *(const float4*)&Wl[k * 132 + c8 * 8];
            float4 w1 = *(const float4*)&Wl[k * 132 + c8 * 8 + 4];
            acc[0] = fmaf(hv, w0.x, acc[0]); acc[1] = fmaf(hv, w0.y, acc[1]);
            acc[2] = fmaf(hv, w0.z, acc[2]); acc[3] = fmaf(hv, w0.w, acc[3]);
            acc[4] = fmaf(hv, w1.x, acc[4]); acc[5] = fmaf(hv, w1.y, acc[5]);
            acc[6] = fmaf(hv, w1.z, acc[6]); acc[7] = fmaf(hv, w1.w, acc[7]);
        }
        *(float4*)&hp[n * 132 + c8 * 8]     = *(float4*)&acc[0];
        *(float4*)&hp[n * 132 + c8 * 8 + 4] = *(float4*)&acc[4];
    }
    __syncthreads();

    // src/dst projections
    if (tid < 64) {
        int h = tid >> 4, n = tid & 15;
        float as = 0.f, ad = 0.f;
        #pragma unroll
        for (int d = 0; d < 32; ++d) {
            float x = hp[n * 132 + h * 32 + d];
            as = fmaf(x, att_a[h * 64 + d], as);
            ad = fmaf(x, att_a[h * 64 + 32 + d], ad);
        }
        srcv[tid] = as; dstv[tid] = ad;
    }
    __syncthreads();

    // attention softmax (leaky_relu 0.2)
    if (tid < 64) {
        int h = tid >> 4;
        float si = srcv[tid];
        float ev[16], m = -1e30f;
        #pragma unroll
        for (int j = 0; j < 16; ++j) {
            float x = si + dstv[h * 16 + j];
            x = (x >= 0.f) ? x : 0.2f * x;
            ev[j] = x; m = fmaxf(m, x);
        }
        float ssum = 0.f;
        #pragma unroll
        for (int j = 0; j < 16; ++j) { float p = expf(ev[j] - m); ev[j] = p; ssum += p; }
        float inv = 1.f / ssum;
        #pragma unroll
        for (int j = 0; j < 16; ++j) attn[tid * 17 + j] = ev[j] * inv;
    }
    __syncthreads();

    // g[h][i][d] = elu(sum_j attn[h][i][j]*hp[j][h*32+d]); thread owns 8 d's
    {
        const int h = tid >> 6, i = (tid >> 2) & 15, dq = tid & 3;
        float acc[8] = {};
        #pragma unroll
        for (int j = 0; j < 16; ++j) {
            float a = attn[(h * 16 + i) * 17 + j];
            float4 g0 = *(const float4*)&hp[j * 132 + h * 32 + dq * 8];
            float4 g1 = *(const float4*)&hp[j * 132 + h * 32 + dq * 8 + 4];
            acc[0] = fmaf(a, g0.x, acc[0]); acc[1] = fmaf(a, g0.y, acc[1]);
            acc[2] = fmaf(a, g0.z, acc[2]); acc[3] = fmaf(a, g0.w, acc[3]);
            acc[4] = fmaf(a, g1.x, acc[4]); acc[5] = fmaf(a, g1.y, acc[5]);
            acc[6] = fmaf(a, g1.z, acc[6]); acc[7] = fmaf(a, g1.w, acc[7]);
        }
        ushort8 o;
        #pragma unroll
        for (int t = 0; t < 8; ++t) {
            float x = acc[t];
            x = (x > 0.f) ? x : expm1f(x);
            o[t] = f2bf(x);
        }
        *(ushort8*)&g_bf[(size_t)b * 2048 + h * 512 + i * 32 + dq * 8] = o;
    }

    // small GEMVs: b1, wf (abs), V1->relu->V2 (v)
    if (tid < 96) {
        int which = tid >> 5, e = tid & 31;
        const float* Wm = (which == 0) ? b1_W : ((which == 1) ? wf_W : V1_W);
        float acc = 0.f;
        #pragma unroll 8
        for (int k = 0; k < 128; ++k) acc = fmaf(sv[k], Wm[k * 32 + e], acc);
        if (which == 0)      b1_out[b * 32 + e] = acc + b1_b[e];
        else if (which == 1) wf_out[b * 32 + e] = fabsf(acc + wf_b[e]);
        else                 red[e] = fmaxf(acc + V1_b[e], 0.f) * V2_W[e];
    }
    __syncthreads();
    if (tid == 0) {
        float acc = V2_b[0];
        #pragma unroll
        for (int e = 0; e < 32; ++e) acc += red[e];
        v_out[b] = acc;
    }
}

// ---------------------------------------------------------------------------
// K2: fused w1_state GEMM (bf16 MFMA, K=128) + uncertainty/bias fixup +
// |w1_state . g| dot + qs contraction. Block = 64 rows x 1 head; 8 col-chunks.
// Writes hid_part[h][row][e] (partial over its head).
// ---------------------------------------------------------------------------
__global__ __launch_bounds__(256, 1) void k2_fused(
    const unsigned short* __restrict__ A_bf,    // [4096][128] bf16
    const unsigned short* __restrict__ w1sT_bf, // [4096 cols][128 k] bf16
    const unsigned short* __restrict__ g_bf,    // [4096][4][16][32] bf16
    const float* __restrict__ agent_qs,         // [4096][16]
    const float* __restrict__ uncertainty,      // [4096]
    const float* __restrict__ w1s_W,            // [129][4096] (row 128 used)
    const float* __restrict__ w1s_b,            // [4096]
    float* __restrict__ hid_part)               // [4][4096][32]
{
    const int r0 = blockIdx.x * 64;   // row tile
    const int h  = blockIdx.y;        // head
    const int tid = threadIdx.x;
    const int wave = tid >> 6, lane = tid & 63;
    const int m = lane & 15, quad = lane >> 4;

    __shared__ unsigned short As[64 * 136];   // [row][k], pad 8
    __shared__ unsigned short Bs[128 * 136];  // [col][k], pad 8
    __shared__ unsigned short Gs[64 * 520];   // [row][n*32+d], pad 8
    __shared__ float Ws[4 * 64 * 36];         // [e][row][d], pad 4
    __shared__ float Qs[64 * 17];             // [row][n], pad 1
    __shared__ float Us[64];

    // ---- one-time staging ----
    #pragma unroll
    for (int t = 0; t < 4; ++t) {             // As: 64x128 bf16
        int i = t * 256 + tid;
        int row = i >> 4, seg = i & 15;
        *(ushort8*)&As[row * 136 + seg * 8] =
            *(const ushort8*)&A_bf[(size_t)(r0 + row) * 128 + seg * 8];
    }
    #pragma unroll
    for (int t = 0; t < 16; ++t) {            // Gs: 64x512 bf16
        int i = t * 256 + tid;
        int row = i >> 6, seg = i & 63;
        *(ushort8*)&Gs[row * 520 + seg * 8] =
            *(const ushort8*)&g_bf[(size_t)(r0 + row) * 2048 + h * 512 + seg * 8];
    }
    #pragma unroll
    for (int t = 0; t < 4; ++t) {             // Qs
        int i = t * 256 + tid;
        int row = i >> 4, n = i & 15;
        Qs[row * 17 + n] = agent_qs[(r0 + row) * 16 + n];
    }
    if (tid < 64) Us[tid] = uncertainty[r0 + tid];
    __syncthreads();

    const float* w128 = &w1s_W[(size_t)128 * 4096];

    for (int chunk = 0; chunk < 8; ++chunk) {
        const int c0 = h * 1024 + chunk * 128;   // global col base

        // stage Bs: 128 cols x 128 k bf16
        #pragma unroll
        for (int t = 0; t < 8; ++t) {
            int i = t * 256 + tid;
            int col = i >> 4, seg = i & 15;
            *(ushort8*)&Bs[col * 136 + seg * 8] =
                *(const ushort8*)&w1sT_bf[(size_t)(c0 + col) * 128 + seg * 8];
        }
        __syncthreads();

        // ---- MFMA: wave handles rows wave*16..+16, all 128 cols ----
        float4v acc[8];
        #pragma unroll
        for (int nt = 0; nt < 8; ++nt) acc[nt] = (float4v){0.f, 0.f, 0.f, 0.f};
        #pragma unroll
        for (int ks = 0; ks < 4; ++ks) {
            short8 a = *(const short8*)&As[(wave * 16 + m) * 136 + ks * 32 + quad * 8];
            #pragma unroll
            for (int nt = 0; nt < 8; ++nt) {
                short8 bfr = *(const short8*)&Bs[(nt * 16 + m) * 136 + ks * 32 + quad * 8];
                acc[nt] = __builtin_amdgcn_mfma_f32_16x16x32_bf16(a, bfr, acc[nt], 0, 0, 0);
            }
        }
        // epilogue: fixup (uncertainty row + bias) and stage to Ws[e][row][d]
        #pragma unroll
        for (int nt = 0; nt < 8; ++nt) {
            int col_l = nt * 16 + m;
            int e = col_l >> 5, d = col_l & 31;
            int cg = c0 + col_l;
            float wfix = w128[cg];
            float bias = w1s_b[cg];
            #pragma unroll
            for (int reg = 0; reg < 4; ++reg) {
                int rl = wave * 16 + quad * 4 + reg;
                Ws[(e * 64 + rl) * 36 + d] = acc[nt][reg] + Us[rl] * wfix + bias;
            }
        }
        __syncthreads();

        // ---- dot phase: thread = (row r = tid&63, e_local = tid>>6) ----
        {
            const int r = tid & 63, el = tid >> 6;
            float w1row[32];
            #pragma unroll
            for (int s = 0; s < 8; ++s)
                *(float4*)&w1row[s * 4] = *(const float4*)&Ws[(el * 64 + r) * 36 + s * 4];
            float acc_e = 0.f;
            #pragma unroll 4
            for (int n = 0; n < 16; ++n) {
                float dp = 0.f;
                #pragma unroll
                for (int seg = 0; seg < 4; ++seg) {
                    ushort8 gv = *(const ushort8*)&Gs[r * 520 + n * 32 + seg * 8];
                    #pragma unroll
                    for (int j = 0; j < 8; ++j)
                        dp = fmaf(w1row[seg * 8 + j], bf2f(gv[j]), dp);
                }
                acc_e = fmaf(Qs[r * 17 + n], fabsf(dp), acc_e);
            }
            hid_part[((size_t)h * 4096 + r0 + r) * 32 + chunk * 4 + el] = acc_e;
        }
        __syncthreads();
    }
}

// ---------------------------------------------------------------------------
// K3: combine heads (mean/4), +b1, elu, *wf, reduce over e, +v -> out
// thread = (row, e); 32-lane shuffle reduce
// ---------------------------------------------------------------------------
__global__ __launch_bounds__(256) void k3_final(
    const float* __restrict__ hid_part,  // [4][4096][32]
    const float* __restrict__ b1v,
    const float* __restrict__ wfv,
    const float* __restrict__ vv,
    float* __restrict__ out)
{
    int idx = blockIdx.x * 256 + threadIdx.x;  // < 131072
    int row = idx >> 5, e = idx & 31;
    const size_t HS = (size_t)4096 * 32;
    size_t o = (size_t)row * 32 + e;
    float s = hid_part[o] + hid_part[HS + o] + hid_part[2 * HS + o] + hid_part[3 * HS + o];
    float hid = 0.25f * s + b1v[o];
    hid = (hid > 0.f) ? hid : expm1f(hid);
    float val = hid * wfv[o];
    #pragma unroll
    for (int off = 16; off > 0; off >>= 1) val += __shfl_down(val, off, 32);
    if ((threadIdx.x & 31) == 0) out[row] = val + vv[row];
}

// ---------------------------------------------------------------------------
extern "C" void kernel_launch(void* const* d_in, const int* in_sizes, int n_in,
                              void* d_out, int out_size, void* d_ws, size_t ws_size,
                              hipStream_t stream)
{
    const float* agent_qs      = (const float*)d_in[0];
    const float* states        = (const float*)d_in[1];
    const float* hidden_states = (const float*)d_in[2];
    const float* uncertainty   = (const float*)d_in[3];
    const float* W_gat         = (const float*)d_in[4];
    const float* att_a         = (const float*)d_in[5];
    const float* w1s_W         = (const float*)d_in[6];
    const float* w1s_b         = (const float*)d_in[7];
    const float* b1_W          = (const float*)d_in[8];
    const float* b1_b          = (const float*)d_in[9];
    const float* wf_W          = (const float*)d_in[10];
    const float* wf_b          = (const float*)d_in[11];
    const float* V1_W          = (const float*)d_in[12];
    const float* V1_b          = (const float*)d_in[13];
    const float* V2_W          = (const float*)d_in[14];
    const float* V2_b          = (const float*)d_in[15];

    char* w = (char*)d_ws;
    unsigned short* g_bf  = (unsigned short*)w;  w += (size_t)4096 * 2048 * 2;
    unsigned short* A_bf  = (unsigned short*)w;  w += (size_t)4096 * 128 * 2;
    unsigned short* w1sT  = (unsigned short*)w;  w += (size_t)4096 * 128 * 2;
    float* b1v            = (float*)w;           w += (size_t)4096 * 32 * 4;
    float* wfv            = (float*)w;           w += (size_t)4096 * 32 * 4;
    float* vv             = (float*)w;           w += (size_t)4096 * 4;
    float* hid_part       = (float*)w;           w += (size_t)4 * 4096 * 32 * 4;
    float* out            = (float*)d_out;

    k0_convert<<<2048, 256, 0, stream>>>(states, w1s_W, A_bf, w1sT);

    k1_gat<<<4096, 256, 0, stream>>>(states, hidden_states, W_gat, att_a,
        b1_W, b1_b, wf_W, wf_b, V1_W, V1_b, V2_W, V2_b, g_bf, b1v, wfv, vv);

    dim3 grid2(64, 4);
    k2_fused<<<grid2, 256, 0, stream>>>(A_bf, w1sT, g_bf, agent_qs, uncertainty,
                                        w1s_W, w1s_b, hid_part);

    k3_final<<<512, 256, 0, stream>>>(hid_part, b1v, wfv, vv, out);
}